// Round 4
// baseline (339.607 us; speedup 1.0000x reference)
//
#include <hip/hip_runtime.h>
#include <math.h>

#define NN 1536
#define DIN 256
#define DOUT 64
#define NWAY 16
#define NSUP 768
#define IB 12     // i-rows per k_e block; 1536/12 = 128 tiles * 6 j-chunks = 768 blocks

// d_out layout (floats): scores[768*16], h_out[1536*64], a[1536*1536]
#define OFF_SCORES 0
#define OFF_H 12288
#define OFF_A 110592

// d_ws layout (floats)
#define WG 0          // g[1536*64]
#define WQ 98304      // q[1536] (pre-scaled by 0.6)
#define WCODE 99840   // code[1536] int: known ? label : -1
#define WCENT 101376  // centroids[16*64]
#define WHP 102400    // h partials [12][1536][64]

// ---------------- g = hidden @ W^T, q_i = 0.6*<w, g_i>, mask code ----------------
__global__ __launch_bounds__(256) void k_g(const float* __restrict__ hid,
                                           const float* __restrict__ W,
                                           const float* __restrict__ attw,
                                           const int* __restrict__ labels,
                                           const int* __restrict__ zda,
                                           float* __restrict__ g,
                                           float* __restrict__ q,
                                           int* __restrict__ code) {
  int t = threadIdx.x;
  int r = t >> 6, d = t & 63;
  int i = blockIdx.x * 4 + r;
  const float4* hp = (const float4*)(hid + (size_t)i * DIN);
  const float4* wp = (const float4*)(W + (size_t)d * DIN);
  float4 acc = {0.f, 0.f, 0.f, 0.f};
#pragma unroll
  for (int k = 0; k < DIN / 4; k++) {
    float4 h4 = hp[k];
    float4 w4 = wp[k];
    acc.x = fmaf(h4.x, w4.x, acc.x);
    acc.y = fmaf(h4.y, w4.y, acc.y);
    acc.z = fmaf(h4.z, w4.z, acc.z);
    acc.w = fmaf(h4.w, w4.w, acc.w);
  }
  float gv = (acc.x + acc.y) + (acc.z + acc.w);
  g[(size_t)i * DOUT + d] = gv;
  float val = gv * attw[d];
#pragma unroll
  for (int off = 32; off >= 1; off >>= 1) val += __shfl_xor(val, off, 64);
  if (d == 0) q[i] = 0.6f * val;
  if (t < 4) {
    int ii = blockIdx.x * 4 + t;
    code[ii] = zda[ii] ? -1 : labels[ii];
  }
}

// ---------------- e[i][j]: grid(128 i-tiles, 6 j-chunks), thread owns j ----------------
// Register-disciplined: launch_bounds(256,4) caps VGPR at 128 (4 blocks/CU);
// u-loop pinned to no-unroll so only gj[16]+acc stay live.
__global__ __launch_bounds__(256, 4) void k_e(const float* __restrict__ g,
                                              const float* __restrict__ q,
                                              const int* __restrict__ code,
                                              const float* __restrict__ attw,
                                              float* __restrict__ aout) {
  __shared__ float gi[IB * DOUT];  // 3 KB
  __shared__ float wl[DOUT];       // 256 B, pre-scaled by 0.4
  __shared__ float qi[IB];
  __shared__ int ci[IB];
  int t = threadIdx.x;
  int i0 = blockIdx.x * IB;
  int j = blockIdx.y * 256 + t;

  if (t < IB * 16) {
    ((float4*)gi)[t] = ((const float4*)(g + (size_t)i0 * DOUT))[t];
  } else if (t < IB * 16 + 16) {
    int k = t - IB * 16;
    float4 w4 = ((const float4*)attw)[k];
    w4.x *= 0.4f; w4.y *= 0.4f; w4.z *= 0.4f; w4.w *= 0.4f;
    ((float4*)wl)[k] = w4;
  } else if (t < IB * 16 + 16 + IB) {
    int u = t - (IB * 16 + 16);
    qi[u] = q[i0 + u];
    ci[u] = code[i0 + u];
  }
  float4 gj[16];
  const float4* gp = (const float4*)(g + (size_t)j * DOUT);
#pragma unroll
  for (int k = 0; k < 16; k++) gj[k] = gp[k];
  float qj = q[j];
  int cj = code[j];
  __syncthreads();

#pragma unroll 1
  for (int u = 0; u < IB; u++) {
    const float4* gv = (const float4*)(gi + u * DOUT);
    const float4* wv = (const float4*)wl;
    float4 acc = {0.f, 0.f, 0.f, 0.f};
#pragma unroll
    for (int k = 0; k < 16; k++) {
      float4 a4 = gv[k];   // wave-uniform LDS broadcast
      float4 w4 = wv[k];   // broadcast
      float4 b4 = gj[k];
      acc.x = fmaf(w4.x, fabsf(a4.x + b4.x), acc.x);
      acc.y = fmaf(w4.y, fabsf(a4.y + b4.y), acc.y);
      acc.z = fmaf(w4.z, fabsf(a4.z + b4.z), acc.z);
      acc.w = fmaf(w4.w, fabsf(a4.w + b4.w), acc.w);
    }
    float e = (qi[u] + qj) + ((acc.x + acc.y) + (acc.z + acc.w));
    int cu = ci[u];
    if ((cu >= 0) && (cj >= 0) && (cu != cj)) e = -1e30f;
    aout[(size_t)(i0 + u) * NN + j] = e;
  }
}

// ---------------- in-place row softmax over the a buffer ----------------
__global__ __launch_bounds__(256) void k_sm(float* __restrict__ a) {
  __shared__ float red[8];
  int i = blockIdx.x, t = threadIdx.x;
  float* row = a + (size_t)i * NN;
  float v[6];
#pragma unroll
  for (int k = 0; k < 6; k++) v[k] = row[t + 256 * k];
  float m = v[0];
#pragma unroll
  for (int k = 1; k < 6; k++) m = fmaxf(m, v[k]);
#pragma unroll
  for (int off = 32; off >= 1; off >>= 1) m = fmaxf(m, __shfl_xor(m, off, 64));
  int w = t >> 6;
  if ((t & 63) == 0) red[w] = m;
  __syncthreads();
  m = fmaxf(fmaxf(red[0], red[1]), fmaxf(red[2], red[3]));
  float s = 0.f;
#pragma unroll
  for (int k = 0; k < 6; k++) {
    v[k] = __expf(v[k] - m);
    s += v[k];
  }
#pragma unroll
  for (int off = 32; off >= 1; off >>= 1) s += __shfl_xor(s, off, 64);
  if ((t & 63) == 0) red[4 + w] = s;
  __syncthreads();
  s = (red[4] + red[5]) + (red[6] + red[7]);
  float inv = 1.f / s;
#pragma unroll
  for (int k = 0; k < 6; k++) row[t + 256 * k] = v[k] * inv;
}

// ---------------- h partial = a[:, chunk] @ g[chunk, :]  grid(96 r-tiles, 12 j-chunks) ----
__global__ __launch_bounds__(256) void k_h(const float* __restrict__ a,
                                           const float* __restrict__ g,
                                           float* __restrict__ hp) {
  __shared__ float at[16 * 132];
  __shared__ float gl[128 * 64];
  int t = threadIdx.x;
  int jc = blockIdx.y;
  int r0 = blockIdx.x * 16;
#pragma unroll
  for (int u = 0; u < 2; u++) {
    int f4 = t + u * 256;
    int row = f4 >> 5;
    int col4 = f4 & 31;
    float4 v = *(const float4*)(a + (size_t)(r0 + row) * NN + jc * 128 + col4 * 4);
    *(float4*)(at + row * 132 + col4 * 4) = v;
  }
  {
    const float4* src = (const float4*)(g + (size_t)jc * 128 * DOUT);
    float4* dst = (float4*)gl;
#pragma unroll
    for (int u = 0; u < 8; u++) dst[t + u * 256] = src[t + u * 256];
  }
  __syncthreads();
  int r = t >> 4;
  int dq = (t & 15) * 4;
  const float4* ap = (const float4*)(at + r * 132);
  float4 acc = {0.f, 0.f, 0.f, 0.f};
  for (int j4 = 0; j4 < 32; j4++) {
    float4 av = ap[j4];
    const float* gb = gl + (j4 * 4) * 64 + dq;
    float4 g0 = *(const float4*)(gb);
    float4 g1 = *(const float4*)(gb + 64);
    float4 g2 = *(const float4*)(gb + 128);
    float4 g3 = *(const float4*)(gb + 192);
    acc.x = fmaf(av.x, g0.x, acc.x); acc.y = fmaf(av.x, g0.y, acc.y);
    acc.z = fmaf(av.x, g0.z, acc.z); acc.w = fmaf(av.x, g0.w, acc.w);
    acc.x = fmaf(av.y, g1.x, acc.x); acc.y = fmaf(av.y, g1.y, acc.y);
    acc.z = fmaf(av.y, g1.z, acc.z); acc.w = fmaf(av.y, g1.w, acc.w);
    acc.x = fmaf(av.z, g2.x, acc.x); acc.y = fmaf(av.z, g2.y, acc.y);
    acc.z = fmaf(av.z, g2.z, acc.z); acc.w = fmaf(av.z, g2.w, acc.w);
    acc.x = fmaf(av.w, g3.x, acc.x); acc.y = fmaf(av.w, g3.y, acc.y);
    acc.z = fmaf(av.w, g3.z, acc.z); acc.w = fmaf(av.w, g3.w, acc.w);
  }
  *(float4*)(hp + ((size_t)jc * NN + r0 + r) * DOUT + dq) = acc;
}

// ---------------- reduce 12 partials -> h_out ----------------
__global__ __launch_bounds__(256) void k_hred(const float* __restrict__ hp,
                                              float* __restrict__ h) {
  int idx = blockIdx.x * 256 + threadIdx.x;
  float s = 0.f;
#pragma unroll
  for (int c = 0; c < 12; c++) s += hp[(size_t)c * (NN * DOUT) + idx];
  h[idx] = s;
}

// ---------------- centroids (one block per class, 1024 threads) ----------------
__global__ __launch_bounds__(1024) void k_cent(const float* __restrict__ h,
                                               const int* __restrict__ labels,
                                               float* __restrict__ cent) {
  __shared__ float part[16][64];
  __shared__ int pc[16];
  int c = blockIdx.x, t = threadIdx.x;
  int d = t & 63, rq = t >> 6;
  float acc = 0.f;
  int cnt = 0;
#pragma unroll 4
  for (int r = rq; r < NSUP; r += 16) {
    int lab = labels[r];
    if (lab == c) { acc += h[(size_t)r * DOUT + d]; cnt++; }
  }
  part[rq][d] = acc;
  if (d == 0) pc[rq] = cnt;
  __syncthreads();
  if (t < 64) {
    float num = 0.f;
    int count = 0;
#pragma unroll
    for (int k = 0; k < 16; k++) { num += part[k][t]; count += pc[k]; }
    cent[c * DOUT + t] = (count > 0) ? (num / (float)count) : 0.f;
  }
}

// ---------------- scores = 1/(dist(query, centroid)+1e-10) ----------------
__global__ __launch_bounds__(256) void k_scores(const float* __restrict__ h,
                                                const float* __restrict__ cent,
                                                float* __restrict__ scores) {
  __shared__ float cl[NWAY * 65];
  __shared__ float hl[16 * 65];
  int t = threadIdx.x;
  int q0 = blockIdx.x * 16;
#pragma unroll
  for (int u = 0; u < 4; u++) {
    int f = t + u * 256;
    int row = f >> 6, k = f & 63;
    cl[row * 65 + k] = cent[f];
    hl[row * 65 + k] = h[(size_t)(NSUP + q0) * DOUT + f];
  }
  __syncthreads();
  int qr = t >> 4, c = t & 15;
  const float* hv = hl + qr * 65;
  const float* cv = cl + c * 65;
  float hh = 0.f, cc = 0.f, hc = 0.f;
#pragma unroll
  for (int k = 0; k < DOUT; k++) {
    float av = hv[k], bv = cv[k];
    hh = fmaf(av, av, hh);
    cc = fmaf(bv, bv, cc);
    hc = fmaf(av, bv, hc);
  }
  float d2 = fmaxf(hh + cc - 2.f * hc, 0.f);
  scores[q0 * NWAY + t] = 1.f / (sqrtf(d2) + 1e-10f);
}

extern "C" void kernel_launch(void* const* d_in, const int* in_sizes, int n_in,
                              void* d_out, int out_size, void* d_ws, size_t ws_size,
                              hipStream_t stream) {
  const float* hid = (const float*)d_in[0];
  const float* W = (const float*)d_in[1];
  const float* attw = (const float*)d_in[2];
  const int* labels = (const int*)d_in[3];
  const int* zda = (const int*)d_in[4];
  float* out = (float*)d_out;
  float* ws = (float*)d_ws;

  float* g = ws + WG;
  float* q = ws + WQ;
  int* code = (int*)(ws + WCODE);
  float* cent = ws + WCENT;
  float* hp = ws + WHP;
  float* scores = out + OFF_SCORES;
  float* h = out + OFF_H;
  float* a = out + OFF_A;

  hipLaunchKernelGGL(k_g, dim3(NN / 4), dim3(256), 0, stream, hid, W, attw, labels, zda, g, q, code);
  hipLaunchKernelGGL(k_e, dim3(NN / IB, NN / 256), dim3(256), 0, stream, g, q, code, attw, a);
  hipLaunchKernelGGL(k_sm, dim3(NN), dim3(256), 0, stream, a);
  hipLaunchKernelGGL(k_h, dim3(NN / 16, NN / 128), dim3(256), 0, stream, a, g, hp);
  hipLaunchKernelGGL(k_hred, dim3(NN * DOUT / 256), dim3(256), 0, stream, hp, h);
  hipLaunchKernelGGL(k_cent, dim3(NWAY), dim3(1024), 0, stream, h, labels, cent);
  hipLaunchKernelGGL(k_scores, dim3(NSUP / 16), dim3(256), 0, stream, h, cent, scores);
}

// Round 5
// 87.111 us; speedup vs baseline: 3.8986x; 3.8986x over previous
//
#include <hip/hip_runtime.h>
#include <math.h>

#define NN 1536
#define DIN 256
#define DOUT 64
#define NWAY 16
#define NSUP 768
#define IB 12     // i-rows per k_e block; 1536/12 = 128 tiles * 6 j-chunks = 768 blocks

// d_out layout (floats): scores[768*16], h_out[1536*64], a[1536*1536]
#define OFF_SCORES 0
#define OFF_H 12288
#define OFF_A 110592

// d_ws layout (floats)
#define WG 0          // g[1536*64]
#define WQ 98304      // q[1536] (pre-scaled by 0.6)
#define WCODE 99840   // code[1536] int: known ? label : -1
#define WCENT 101376  // centroids[16*64]
#define WHP 102400    // h partials [12][1536][64]

// ---------------- g = hidden @ W^T, q_i = 0.6*<w, g_i>, mask code ----------------
__global__ __launch_bounds__(256) void k_g(const float* __restrict__ hid,
                                           const float* __restrict__ W,
                                           const float* __restrict__ attw,
                                           const int* __restrict__ labels,
                                           const int* __restrict__ zda,
                                           float* __restrict__ g,
                                           float* __restrict__ q,
                                           int* __restrict__ code) {
  int t = threadIdx.x;
  int r = t >> 6, d = t & 63;
  int i = blockIdx.x * 4 + r;
  const float4* hp = (const float4*)(hid + (size_t)i * DIN);
  const float4* wp = (const float4*)(W + (size_t)d * DIN);
  float4 acc = {0.f, 0.f, 0.f, 0.f};
#pragma unroll
  for (int k = 0; k < DIN / 4; k++) {
    float4 h4 = hp[k];
    float4 w4 = wp[k];
    acc.x = fmaf(h4.x, w4.x, acc.x);
    acc.y = fmaf(h4.y, w4.y, acc.y);
    acc.z = fmaf(h4.z, w4.z, acc.z);
    acc.w = fmaf(h4.w, w4.w, acc.w);
  }
  float gv = (acc.x + acc.y) + (acc.z + acc.w);
  g[(size_t)i * DOUT + d] = gv;
  float val = gv * attw[d];
#pragma unroll
  for (int off = 32; off >= 1; off >>= 1) val += __shfl_xor(val, off, 64);
  if (d == 0) q[i] = 0.6f * val;
  if (t < 4) {
    int ii = blockIdx.x * 4 + t;
    code[ii] = zda[ii] ? -1 : labels[ii];
  }
}

// ---------------- e[i][j]: grid(128 i-tiles, 6 j-chunks), thread owns j ----------------
// gj[16] in VGPRs; gi broadcast from LDS; attn_w read via uniform kernel-arg
// pointer -> s_load (SGPR, zero VGPR cost, not hoist-bloating the VGPR file).
__global__ __launch_bounds__(256, 2) void k_e(const float* __restrict__ g,
                                              const float* __restrict__ q,
                                              const int* __restrict__ code,
                                              const float* __restrict__ attw,
                                              float* __restrict__ aout) {
  __shared__ float gi[IB * DOUT];  // 3 KB
  __shared__ float qi[IB];
  __shared__ int ci[IB];
  int t = threadIdx.x;
  int i0 = blockIdx.x * IB;
  int j = blockIdx.y * 256 + t;

  if (t < IB * 16) {
    ((float4*)gi)[t] = ((const float4*)(g + (size_t)i0 * DOUT))[t];
  } else if (t < IB * 16 + IB) {
    int u = t - IB * 16;
    qi[u] = q[i0 + u];
    ci[u] = code[i0 + u];
  }
  float4 gj[16];
  const float4* gp = (const float4*)(g + (size_t)j * DOUT);
#pragma unroll
  for (int k = 0; k < 16; k++) gj[k] = gp[k];
  float qj = q[j];
  int cj = code[j];
  __syncthreads();

  const float4* wv = (const float4*)attw;  // uniform address -> scalar loads
#pragma unroll 1
  for (int u = 0; u < IB; u++) {
    const float4* gv = (const float4*)(gi + u * DOUT);
    float4 acc = {0.f, 0.f, 0.f, 0.f};
#pragma unroll
    for (int k = 0; k < 16; k++) {
      float4 a4 = gv[k];   // wave-uniform LDS broadcast
      float4 w4 = wv[k];   // SGPR
      float4 b4 = gj[k];
      acc.x = fmaf(w4.x, fabsf(a4.x + b4.x), acc.x);
      acc.y = fmaf(w4.y, fabsf(a4.y + b4.y), acc.y);
      acc.z = fmaf(w4.z, fabsf(a4.z + b4.z), acc.z);
      acc.w = fmaf(w4.w, fabsf(a4.w + b4.w), acc.w);
    }
    float e = (qi[u] + qj) + 0.4f * ((acc.x + acc.y) + (acc.z + acc.w));
    int cu = ci[u];
    if ((cu >= 0) && (cj >= 0) && (cu != cj)) e = -1e30f;
    aout[(size_t)(i0 + u) * NN + j] = e;
  }
}

// ---------------- in-place row softmax over the a buffer ----------------
__global__ __launch_bounds__(256) void k_sm(float* __restrict__ a) {
  __shared__ float red[8];
  int i = blockIdx.x, t = threadIdx.x;
  float* row = a + (size_t)i * NN;
  float v[6];
#pragma unroll
  for (int k = 0; k < 6; k++) v[k] = row[t + 256 * k];
  float m = v[0];
#pragma unroll
  for (int k = 1; k < 6; k++) m = fmaxf(m, v[k]);
#pragma unroll
  for (int off = 32; off >= 1; off >>= 1) m = fmaxf(m, __shfl_xor(m, off, 64));
  int w = t >> 6;
  if ((t & 63) == 0) red[w] = m;
  __syncthreads();
  m = fmaxf(fmaxf(red[0], red[1]), fmaxf(red[2], red[3]));
  float s = 0.f;
#pragma unroll
  for (int k = 0; k < 6; k++) {
    v[k] = __expf(v[k] - m);
    s += v[k];
  }
#pragma unroll
  for (int off = 32; off >= 1; off >>= 1) s += __shfl_xor(s, off, 64);
  if ((t & 63) == 0) red[4 + w] = s;
  __syncthreads();
  s = (red[4] + red[5]) + (red[6] + red[7]);
  float inv = 1.f / s;
#pragma unroll
  for (int k = 0; k < 6; k++) row[t + 256 * k] = v[k] * inv;
}

// ---------------- h partial = a[:, chunk] @ g[chunk, :]  grid(96 r-tiles, 12 j-chunks) ----
__global__ __launch_bounds__(256) void k_h(const float* __restrict__ a,
                                           const float* __restrict__ g,
                                           float* __restrict__ hp) {
  __shared__ float at[16 * 132];
  __shared__ float gl[128 * 64];
  int t = threadIdx.x;
  int jc = blockIdx.y;
  int r0 = blockIdx.x * 16;
#pragma unroll
  for (int u = 0; u < 2; u++) {
    int f4 = t + u * 256;
    int row = f4 >> 5;
    int col4 = f4 & 31;
    float4 v = *(const float4*)(a + (size_t)(r0 + row) * NN + jc * 128 + col4 * 4);
    *(float4*)(at + row * 132 + col4 * 4) = v;
  }
  {
    const float4* src = (const float4*)(g + (size_t)jc * 128 * DOUT);
    float4* dst = (float4*)gl;
#pragma unroll
    for (int u = 0; u < 8; u++) dst[t + u * 256] = src[t + u * 256];
  }
  __syncthreads();
  int r = t >> 4;
  int dq = (t & 15) * 4;
  const float4* ap = (const float4*)(at + r * 132);
  float4 acc = {0.f, 0.f, 0.f, 0.f};
  for (int j4 = 0; j4 < 32; j4++) {
    float4 av = ap[j4];
    const float* gb = gl + (j4 * 4) * 64 + dq;
    float4 g0 = *(const float4*)(gb);
    float4 g1 = *(const float4*)(gb + 64);
    float4 g2 = *(const float4*)(gb + 128);
    float4 g3 = *(const float4*)(gb + 192);
    acc.x = fmaf(av.x, g0.x, acc.x); acc.y = fmaf(av.x, g0.y, acc.y);
    acc.z = fmaf(av.x, g0.z, acc.z); acc.w = fmaf(av.x, g0.w, acc.w);
    acc.x = fmaf(av.y, g1.x, acc.x); acc.y = fmaf(av.y, g1.y, acc.y);
    acc.z = fmaf(av.y, g1.z, acc.z); acc.w = fmaf(av.y, g1.w, acc.w);
    acc.x = fmaf(av.z, g2.x, acc.x); acc.y = fmaf(av.z, g2.y, acc.y);
    acc.z = fmaf(av.z, g2.z, acc.z); acc.w = fmaf(av.z, g2.w, acc.w);
    acc.x = fmaf(av.w, g3.x, acc.x); acc.y = fmaf(av.w, g3.y, acc.y);
    acc.z = fmaf(av.w, g3.z, acc.z); acc.w = fmaf(av.w, g3.w, acc.w);
  }
  *(float4*)(hp + ((size_t)jc * NN + r0 + r) * DOUT + dq) = acc;
}

// ---------------- reduce 12 partials -> h_out ----------------
__global__ __launch_bounds__(256) void k_hred(const float* __restrict__ hp,
                                              float* __restrict__ h) {
  int idx = blockIdx.x * 256 + threadIdx.x;
  float s = 0.f;
#pragma unroll
  for (int c = 0; c < 12; c++) s += hp[(size_t)c * (NN * DOUT) + idx];
  h[idx] = s;
}

// ---------------- centroids (one block per class, 1024 threads) ----------------
__global__ __launch_bounds__(1024) void k_cent(const float* __restrict__ h,
                                               const int* __restrict__ labels,
                                               float* __restrict__ cent) {
  __shared__ float part[16][64];
  __shared__ int pc[16];
  int c = blockIdx.x, t = threadIdx.x;
  int d = t & 63, rq = t >> 6;
  float acc = 0.f;
  int cnt = 0;
#pragma unroll 4
  for (int r = rq; r < NSUP; r += 16) {
    int lab = labels[r];
    if (lab == c) { acc += h[(size_t)r * DOUT + d]; cnt++; }
  }
  part[rq][d] = acc;
  if (d == 0) pc[rq] = cnt;
  __syncthreads();
  if (t < 64) {
    float num = 0.f;
    int count = 0;
#pragma unroll
    for (int k = 0; k < 16; k++) { num += part[k][t]; count += pc[k]; }
    cent[c * DOUT + t] = (count > 0) ? (num / (float)count) : 0.f;
  }
}

// ---------------- scores = 1/(dist(query, centroid)+1e-10) ----------------
__global__ __launch_bounds__(256) void k_scores(const float* __restrict__ h,
                                                const float* __restrict__ cent,
                                                float* __restrict__ scores) {
  __shared__ float cl[NWAY * 65];
  __shared__ float hl[16 * 65];
  int t = threadIdx.x;
  int q0 = blockIdx.x * 16;
#pragma unroll
  for (int u = 0; u < 4; u++) {
    int f = t + u * 256;
    int row = f >> 6, k = f & 63;
    cl[row * 65 + k] = cent[f];
    hl[row * 65 + k] = h[(size_t)(NSUP + q0) * DOUT + f];
  }
  __syncthreads();
  int qr = t >> 4, c = t & 15;
  const float* hv = hl + qr * 65;
  const float* cv = cl + c * 65;
  float hh = 0.f, cc = 0.f, hc = 0.f;
#pragma unroll
  for (int k = 0; k < DOUT; k++) {
    float av = hv[k], bv = cv[k];
    hh = fmaf(av, av, hh);
    cc = fmaf(bv, bv, cc);
    hc = fmaf(av, bv, hc);
  }
  float d2 = fmaxf(hh + cc - 2.f * hc, 0.f);
  scores[q0 * NWAY + t] = 1.f / (sqrtf(d2) + 1e-10f);
}

extern "C" void kernel_launch(void* const* d_in, const int* in_sizes, int n_in,
                              void* d_out, int out_size, void* d_ws, size_t ws_size,
                              hipStream_t stream) {
  const float* hid = (const float*)d_in[0];
  const float* W = (const float*)d_in[1];
  const float* attw = (const float*)d_in[2];
  const int* labels = (const int*)d_in[3];
  const int* zda = (const int*)d_in[4];
  float* out = (float*)d_out;
  float* ws = (float*)d_ws;

  float* g = ws + WG;
  float* q = ws + WQ;
  int* code = (int*)(ws + WCODE);
  float* cent = ws + WCENT;
  float* hp = ws + WHP;
  float* scores = out + OFF_SCORES;
  float* h = out + OFF_H;
  float* a = out + OFF_A;

  hipLaunchKernelGGL(k_g, dim3(NN / 4), dim3(256), 0, stream, hid, W, attw, labels, zda, g, q, code);
  hipLaunchKernelGGL(k_e, dim3(NN / IB, NN / 256), dim3(256), 0, stream, g, q, code, attw, a);
  hipLaunchKernelGGL(k_sm, dim3(NN), dim3(256), 0, stream, a);
  hipLaunchKernelGGL(k_h, dim3(NN / 16, NN / 128), dim3(256), 0, stream, a, g, hp);
  hipLaunchKernelGGL(k_hred, dim3(NN * DOUT / 256), dim3(256), 0, stream, hp, h);
  hipLaunchKernelGGL(k_cent, dim3(NWAY), dim3(1024), 0, stream, h, labels, cent);
  hipLaunchKernelGGL(k_scores, dim3(NSUP / 16), dim3(256), 0, stream, h, cent, scores);
}

// Round 7
// 77.620 us; speedup vs baseline: 4.3752x; 1.1223x over previous
//
#include <hip/hip_runtime.h>
#include <math.h>

#define NN 1536
#define DIN 256
#define DOUT 64
#define NWAY 16
#define NSUP 768
#define IB 12     // i-rows per k_e block
#define JBLK 128  // j per k_e block (2 wave-pairs x 64)

// d_out layout (floats): scores[768*16], h_out[1536*64], a[1536*1536]
#define OFF_SCORES 0
#define OFF_H 12288
#define OFF_A 110592

// d_ws layout (floats)
#define WG 0          // g[1536*64]
#define WQ 98304      // q[1536] (pre-scaled by 0.6)
#define WCODE 99840   // code[1536] int: known ? label : -1
#define WCENT 101376  // centroids[16*64]
#define WHP 102400    // h partials [12][1536][64]

// ---------------- g = hidden @ W^T, q_i = 0.6*<w, g_i>, mask code ----------------
__global__ __launch_bounds__(256) void k_g(const float* __restrict__ hid,
                                           const float* __restrict__ W,
                                           const float* __restrict__ attw,
                                           const int* __restrict__ labels,
                                           const int* __restrict__ zda,
                                           float* __restrict__ g,
                                           float* __restrict__ q,
                                           int* __restrict__ code) {
  int t = threadIdx.x;
  int r = t >> 6, d = t & 63;
  int i = blockIdx.x * 4 + r;
  const float4* hp = (const float4*)(hid + (size_t)i * DIN);
  const float4* wp = (const float4*)(W + (size_t)d * DIN);
  float4 acc = {0.f, 0.f, 0.f, 0.f};
#pragma unroll
  for (int k = 0; k < DIN / 4; k++) {
    float4 h4 = hp[k];
    float4 w4 = wp[k];
    acc.x = fmaf(h4.x, w4.x, acc.x);
    acc.y = fmaf(h4.y, w4.y, acc.y);
    acc.z = fmaf(h4.z, w4.z, acc.z);
    acc.w = fmaf(h4.w, w4.w, acc.w);
  }
  float gv = (acc.x + acc.y) + (acc.z + acc.w);
  g[(size_t)i * DOUT + d] = gv;
  float val = gv * attw[d];
#pragma unroll
  for (int off = 32; off >= 1; off >>= 1) val += __shfl_xor(val, off, 64);
  if (d == 0) q[i] = 0.6f * val;
  if (t < 4) {
    int ii = blockIdx.x * 4 + t;
    code[ii] = zda[ii] ? -1 : labels[ii];
  }
}

// ---- e[i][j]: wave-split dims. Wave w: dim-half (w&1), j-group (w>>1). ----
// Per-thread gj = 32 dims (8 float4); attn_w half is wave-uniform -> SGPR loads.
// Per-i half-sums go to LDS; combine pass adds halves, applies q & mask, stores.
__global__ __launch_bounds__(256, 3) void k_e(const float* __restrict__ g,
                                              const float* __restrict__ q,
                                              const int* __restrict__ code,
                                              const float* __restrict__ attw,
                                              float* __restrict__ aout) {
  __shared__ float gis[IB * DOUT];      // 3 KB
  __shared__ float lds_p[4][IB][64];    // 12 KB half-sums
  __shared__ float qi[IB];
  __shared__ int ci[IB];
  int t = threadIdx.x;
  int lane = t & 63;
  int w = t >> 6;
  int whalf = __builtin_amdgcn_readfirstlane(w & 1);
  int jhi = w >> 1;
  int i0 = blockIdx.x * IB;
  int j0 = blockIdx.y * JBLK;
  int j = j0 + jhi * 64 + lane;

  if (t < IB * 16) {   // 192 float4 = 12 rows x 64 floats
    ((float4*)gis)[t] = ((const float4*)(g + (size_t)i0 * DOUT))[t];
  } else if (t < IB * 16 + IB) {
    int u = t - IB * 16;
    qi[u] = q[i0 + u];
    ci[u] = code[i0 + u];
  }
  float4 gj[8];
  const float4* gp = (const float4*)(g + (size_t)j * DOUT + whalf * 32);
#pragma unroll
  for (int k = 0; k < 8; k++) gj[k] = gp[k];
  const float4* wv = (const float4*)(attw + whalf * 32);  // SGPR-uniform
  __syncthreads();

#pragma unroll 1
  for (int u = 0; u < IB; u++) {
    const float4* gv = (const float4*)(gis + u * DOUT + whalf * 32);
    float4 acc = {0.f, 0.f, 0.f, 0.f};
#pragma unroll
    for (int k = 0; k < 8; k++) {
      float4 a4 = gv[k];   // wave-uniform LDS broadcast
      float4 w4 = wv[k];   // SGPR
      float4 b4 = gj[k];
      acc.x = fmaf(w4.x, fabsf(a4.x + b4.x), acc.x);
      acc.y = fmaf(w4.y, fabsf(a4.y + b4.y), acc.y);
      acc.z = fmaf(w4.z, fabsf(a4.z + b4.z), acc.z);
      acc.w = fmaf(w4.w, fabsf(a4.w + b4.w), acc.w);
    }
    lds_p[w][u][lane] = (acc.x + acc.y) + (acc.z + acc.w);
  }
  __syncthreads();

  // combine: thread t handles j_local = t&127 for 6 u's
  int jl = t & 127;
  int sb = (jl >> 6) * 2;       // source wave base: {0,1} or {2,3}
  int ll = jl & 63;
  int jg = j0 + jl;
  float qj = q[jg];
  int cj = code[jg];
  int u0 = (t >> 7) * 6;
#pragma unroll
  for (int v = 0; v < 6; v++) {
    int u = u0 + v;
    float s = lds_p[sb][u][ll] + lds_p[sb + 1][u][ll];
    float e = (qi[u] + qj) + 0.4f * s;
    int cu = ci[u];
    if ((cu >= 0) && (cj >= 0) && (cu != cj)) e = -1e30f;
    aout[(size_t)(i0 + u) * NN + jg] = e;
  }
}

// ---------------- in-place row softmax over the a buffer ----------------
__global__ __launch_bounds__(256) void k_sm(float* __restrict__ a) {
  __shared__ float red[8];
  int i = blockIdx.x, t = threadIdx.x;
  float* row = a + (size_t)i * NN;
  float v[6];
#pragma unroll
  for (int k = 0; k < 6; k++) v[k] = row[t + 256 * k];
  float m = v[0];
#pragma unroll
  for (int k = 1; k < 6; k++) m = fmaxf(m, v[k]);
#pragma unroll
  for (int off = 32; off >= 1; off >>= 1) m = fmaxf(m, __shfl_xor(m, off, 64));
  int w = t >> 6;
  if ((t & 63) == 0) red[w] = m;
  __syncthreads();
  m = fmaxf(fmaxf(red[0], red[1]), fmaxf(red[2], red[3]));
  float s = 0.f;
#pragma unroll
  for (int k = 0; k < 6; k++) {
    v[k] = __expf(v[k] - m);
    s += v[k];
  }
#pragma unroll
  for (int off = 32; off >= 1; off >>= 1) s += __shfl_xor(s, off, 64);
  if ((t & 63) == 0) red[4 + w] = s;
  __syncthreads();
  s = (red[4] + red[5]) + (red[6] + red[7]);
  float inv = 1.f / s;
#pragma unroll
  for (int k = 0; k < 6; k++) row[t + 256 * k] = v[k] * inv;
}

// ------ h partial = a[:, chunk] @ g[chunk, :]  grid(96 r-tiles, 12 j-chunks) ------
__global__ __launch_bounds__(256) void k_h(const float* __restrict__ a,
                                           const float* __restrict__ g,
                                           float* __restrict__ hp) {
  __shared__ float at[16 * 132];
  __shared__ float gl[128 * 64];
  int t = threadIdx.x;
  int jc = blockIdx.y;
  int r0 = blockIdx.x * 16;
#pragma unroll
  for (int u = 0; u < 2; u++) {
    int f4 = t + u * 256;
    int row = f4 >> 5;
    int col4 = f4 & 31;
    float4 v = *(const float4*)(a + (size_t)(r0 + row) * NN + jc * 128 + col4 * 4);
    *(float4*)(at + row * 132 + col4 * 4) = v;
  }
  {
    const float4* src = (const float4*)(g + (size_t)jc * 128 * DOUT);
    float4* dst = (float4*)gl;
#pragma unroll
    for (int u = 0; u < 8; u++) dst[t + u * 256] = src[t + u * 256];
  }
  __syncthreads();
  int r = t >> 4;
  int dq = (t & 15) * 4;
  const float4* ap = (const float4*)(at + r * 132);
  float4 acc = {0.f, 0.f, 0.f, 0.f};
  for (int j4 = 0; j4 < 32; j4++) {
    float4 av = ap[j4];
    const float* gb = gl + (j4 * 4) * 64 + dq;
    float4 g0 = *(const float4*)(gb);
    float4 g1 = *(const float4*)(gb + 64);
    float4 g2 = *(const float4*)(gb + 128);
    float4 g3 = *(const float4*)(gb + 192);
    acc.x = fmaf(av.x, g0.x, acc.x); acc.y = fmaf(av.x, g0.y, acc.y);
    acc.z = fmaf(av.x, g0.z, acc.z); acc.w = fmaf(av.x, g0.w, acc.w);
    acc.x = fmaf(av.y, g1.x, acc.x); acc.y = fmaf(av.y, g1.y, acc.y);
    acc.z = fmaf(av.y, g1.z, acc.z); acc.w = fmaf(av.y, g1.w, acc.w);
    acc.x = fmaf(av.z, g2.x, acc.x); acc.y = fmaf(av.z, g2.y, acc.y);
    acc.z = fmaf(av.z, g2.z, acc.z); acc.w = fmaf(av.z, g2.w, acc.w);
    acc.x = fmaf(av.w, g3.x, acc.x); acc.y = fmaf(av.w, g3.y, acc.y);
    acc.z = fmaf(av.w, g3.z, acc.z); acc.w = fmaf(av.w, g3.w, acc.w);
  }
  *(float4*)(hp + ((size_t)jc * NN + r0 + r) * DOUT + dq) = acc;
}

// ---------------- reduce 12 partials -> h_out ----------------
__global__ __launch_bounds__(256) void k_hred(const float* __restrict__ hp,
                                              float* __restrict__ h) {
  int idx = blockIdx.x * 256 + threadIdx.x;
  float s = 0.f;
#pragma unroll
  for (int c = 0; c < 12; c++) s += hp[(size_t)c * (NN * DOUT) + idx];
  h[idx] = s;
}

// ---------------- centroids (one block per class, 1024 threads) ----------------
__global__ __launch_bounds__(1024) void k_cent(const float* __restrict__ h,
                                               const int* __restrict__ labels,
                                               float* __restrict__ cent) {
  __shared__ float part[16][64];
  __shared__ int pc[16];
  int c = blockIdx.x, t = threadIdx.x;
  int d = t & 63, rq = t >> 6;
  float acc = 0.f;
  int cnt = 0;
#pragma unroll 4
  for (int r = rq; r < NSUP; r += 16) {
    int lab = labels[r];
    if (lab == c) { acc += h[(size_t)r * DOUT + d]; cnt++; }
  }
  part[rq][d] = acc;
  if (d == 0) pc[rq] = cnt;
  __syncthreads();
  if (t < 64) {
    float num = 0.f;
    int count = 0;
#pragma unroll
    for (int k = 0; k < 16; k++) { num += part[k][t]; count += pc[k]; }
    cent[c * DOUT + t] = (count > 0) ? (num / (float)count) : 0.f;
  }
}

// ---------------- scores = 1/(dist(query, centroid)+1e-10) ----------------
__global__ __launch_bounds__(256) void k_scores(const float* __restrict__ h,
                                                const float* __restrict__ cent,
                                                float* __restrict__ scores) {
  __shared__ float cl[NWAY * 65];
  __shared__ float hl[16 * 65];
  int t = threadIdx.x;
  int q0 = blockIdx.x * 16;
#pragma unroll
  for (int u = 0; u < 4; u++) {
    int f = t + u * 256;
    int row = f >> 6, k = f & 63;
    cl[row * 65 + k] = cent[f];
    hl[row * 65 + k] = h[(size_t)(NSUP + q0) * DOUT + f];
  }
  __syncthreads();
  int qr = t >> 4, c = t & 15;
  const float* hv = hl + qr * 65;
  const float* cv = cl + c * 65;
  float hh = 0.f, cc = 0.f, hc = 0.f;
#pragma unroll
  for (int k = 0; k < DOUT; k++) {
    float av = hv[k], bv = cv[k];
    hh = fmaf(av, av, hh);
    cc = fmaf(bv, bv, cc);
    hc = fmaf(av, bv, hc);
  }
  float d2 = fmaxf(hh + cc - 2.f * hc, 0.f);
  scores[q0 * NWAY + t] = 1.f / (sqrtf(d2) + 1e-10f);
}

extern "C" void kernel_launch(void* const* d_in, const int* in_sizes, int n_in,
                              void* d_out, int out_size, void* d_ws, size_t ws_size,
                              hipStream_t stream) {
  const float* hid = (const float*)d_in[0];
  const float* W = (const float*)d_in[1];
  const float* attw = (const float*)d_in[2];
  const int* labels = (const int*)d_in[3];
  const int* zda = (const int*)d_in[4];
  float* out = (float*)d_out;
  float* ws = (float*)d_ws;

  float* g = ws + WG;
  float* q = ws + WQ;
  int* code = (int*)(ws + WCODE);
  float* cent = ws + WCENT;
  float* hp = ws + WHP;
  float* scores = out + OFF_SCORES;
  float* h = out + OFF_H;
  float* a = out + OFF_A;

  hipLaunchKernelGGL(k_g, dim3(NN / 4), dim3(256), 0, stream, hid, W, attw, labels, zda, g, q, code);
  hipLaunchKernelGGL(k_e, dim3(NN / IB, NN / JBLK), dim3(256), 0, stream, g, q, code, attw, a);
  hipLaunchKernelGGL(k_sm, dim3(NN), dim3(256), 0, stream, a);
  hipLaunchKernelGGL(k_h, dim3(NN / 16, NN / 128), dim3(256), 0, stream, a, g, hp);
  hipLaunchKernelGGL(k_hred, dim3(NN * DOUT / 256), dim3(256), 0, stream, hp, h);
  hipLaunchKernelGGL(k_cent, dim3(NWAY), dim3(1024), 0, stream, h, labels, cent);
  hipLaunchKernelGGL(k_scores, dim3(NSUP / 16), dim3(256), 0, stream, h, cent, scores);
}

// Round 8
// 72.013 us; speedup vs baseline: 4.7159x; 1.0779x over previous
//
#include <hip/hip_runtime.h>
#include <math.h>

#define NN 1536
#define DIN 256
#define DOUT 64
#define NWAY 16
#define NSUP 768
#define IB 12     // i-rows per k_e block
#define JBLK 128  // j per k_e block (2 wave-pairs x 64)
#define SROWS 6   // rows per k_smh block; 1536/6 = 256 blocks = 1/CU

// d_out layout (floats): scores[768*16], h_out[1536*64], a[1536*1536]
#define OFF_SCORES 0
#define OFF_H 12288
#define OFF_A 110592

// d_ws layout (floats)
#define WG 0          // g[1536*64]
#define WQ 98304      // q[1536] (pre-scaled by 0.6)
#define WCODE 99840   // code[1536] int: known ? label : -1
#define WCENT 101376  // centroids[16*64]

// ---------------- g = hidden @ W^T, q_i = 0.6*<w, g_i>, mask code ----------------
__global__ __launch_bounds__(256) void k_g(const float* __restrict__ hid,
                                           const float* __restrict__ W,
                                           const float* __restrict__ attw,
                                           const int* __restrict__ labels,
                                           const int* __restrict__ zda,
                                           float* __restrict__ g,
                                           float* __restrict__ q,
                                           int* __restrict__ code) {
  int t = threadIdx.x;
  int r = t >> 6, d = t & 63;
  int i = blockIdx.x * 4 + r;
  const float4* hp = (const float4*)(hid + (size_t)i * DIN);
  const float4* wp = (const float4*)(W + (size_t)d * DIN);
  float4 acc = {0.f, 0.f, 0.f, 0.f};
#pragma unroll
  for (int k = 0; k < DIN / 4; k++) {
    float4 h4 = hp[k];
    float4 w4 = wp[k];
    acc.x = fmaf(h4.x, w4.x, acc.x);
    acc.y = fmaf(h4.y, w4.y, acc.y);
    acc.z = fmaf(h4.z, w4.z, acc.z);
    acc.w = fmaf(h4.w, w4.w, acc.w);
  }
  float gv = (acc.x + acc.y) + (acc.z + acc.w);
  g[(size_t)i * DOUT + d] = gv;
  float val = gv * attw[d];
#pragma unroll
  for (int off = 32; off >= 1; off >>= 1) val += __shfl_xor(val, off, 64);
  if (d == 0) q[i] = 0.6f * val;
  if (t < 4) {
    int ii = blockIdx.x * 4 + t;
    code[ii] = zda[ii] ? -1 : labels[ii];
  }
}

// ---- e[i][j]: wave-split dims. Wave w: dim-half (w&1), j-group (w>>1). ----
__global__ __launch_bounds__(256, 3) void k_e(const float* __restrict__ g,
                                              const float* __restrict__ q,
                                              const int* __restrict__ code,
                                              const float* __restrict__ attw,
                                              float* __restrict__ aout) {
  __shared__ float gis[IB * DOUT];      // 3 KB
  __shared__ float lds_p[4][IB][64];    // 12 KB half-sums
  __shared__ float qi[IB];
  __shared__ int ci[IB];
  int t = threadIdx.x;
  int lane = t & 63;
  int w = t >> 6;
  int whalf = __builtin_amdgcn_readfirstlane(w & 1);
  int jhi = w >> 1;
  int i0 = blockIdx.x * IB;
  int j0 = blockIdx.y * JBLK;
  int j = j0 + jhi * 64 + lane;

  if (t < IB * 16) {
    ((float4*)gis)[t] = ((const float4*)(g + (size_t)i0 * DOUT))[t];
  } else if (t < IB * 16 + IB) {
    int u = t - IB * 16;
    qi[u] = q[i0 + u];
    ci[u] = code[i0 + u];
  }
  float4 gj[8];
  const float4* gp = (const float4*)(g + (size_t)j * DOUT + whalf * 32);
#pragma unroll
  for (int k = 0; k < 8; k++) gj[k] = gp[k];
  const float4* wv = (const float4*)(attw + whalf * 32);  // SGPR-uniform
  __syncthreads();

#pragma unroll 1
  for (int u = 0; u < IB; u++) {
    const float4* gv = (const float4*)(gis + u * DOUT + whalf * 32);
    float4 acc = {0.f, 0.f, 0.f, 0.f};
#pragma unroll
    for (int k = 0; k < 8; k++) {
      float4 a4 = gv[k];   // wave-uniform LDS broadcast
      float4 w4 = wv[k];   // SGPR
      float4 b4 = gj[k];
      acc.x = fmaf(w4.x, fabsf(a4.x + b4.x), acc.x);
      acc.y = fmaf(w4.y, fabsf(a4.y + b4.y), acc.y);
      acc.z = fmaf(w4.z, fabsf(a4.z + b4.z), acc.z);
      acc.w = fmaf(w4.w, fabsf(a4.w + b4.w), acc.w);
    }
    lds_p[w][u][lane] = (acc.x + acc.y) + (acc.z + acc.w);
  }
  __syncthreads();

  int jl = t & 127;
  int sb = (jl >> 6) * 2;
  int ll = jl & 63;
  int jg = j0 + jl;
  float qj = q[jg];
  int cj = code[jg];
  int u0 = (t >> 7) * 6;
#pragma unroll
  for (int v = 0; v < 6; v++) {
    int u = u0 + v;
    float s = lds_p[sb][u][ll] + lds_p[sb + 1][u][ll];
    float e = (qi[u] + qj) + 0.4f * s;
    int cu = ci[u];
    if ((cu >= 0) && (cj >= 0) && (cu != cj)) e = -1e30f;
    aout[(size_t)(i0 + u) * NN + jg] = e;
  }
}

// ---- fused: row softmax (in-place on a) + h = a @ g, 6 rows per block ----
__global__ __launch_bounds__(512) void k_smh(float* __restrict__ a,
                                             const float* __restrict__ g,
                                             float* __restrict__ h) {
  __shared__ float al[SROWS][NN];        // 36 KB normalized a
  __shared__ float part[32][SROWS][68];  // 52.2 KB h partials (pad 68: no bank conflict)
  __shared__ float red[16];
  int t = threadIdx.x;      // 0..511
  int lane = t & 63;
  int w = t >> 6;           // 8 waves
  int r0 = blockIdx.x * SROWS;

  // --- per-row softmax ---
#pragma unroll 1
  for (int r = 0; r < SROWS; r++) {
    float* row = a + (size_t)(r0 + r) * NN;
    float v0 = row[t], v1 = row[t + 512], v2 = row[t + 1024];
    float m = fmaxf(fmaxf(v0, v1), v2);
#pragma unroll
    for (int off = 32; off >= 1; off >>= 1) m = fmaxf(m, __shfl_xor(m, off, 64));
    if (lane == 0) red[w] = m;
    __syncthreads();
    m = red[0];
#pragma unroll
    for (int k = 1; k < 8; k++) m = fmaxf(m, red[k]);
    v0 = __expf(v0 - m);
    v1 = __expf(v1 - m);
    v2 = __expf(v2 - m);
    float s = (v0 + v1) + v2;
#pragma unroll
    for (int off = 32; off >= 1; off >>= 1) s += __shfl_xor(s, off, 64);
    if (lane == 0) red[8 + w] = s;
    __syncthreads();
    s = red[8];
#pragma unroll
    for (int k = 1; k < 8; k++) s += red[8 + k];
    float inv = 1.f / s;
    v0 *= inv; v1 *= inv; v2 *= inv;
    al[r][t] = v0; al[r][t + 512] = v1; al[r][t + 1024] = v2;
    row[t] = v0; row[t + 512] = v1; row[t + 1024] = v2;
    __syncthreads();   // red reused next iteration; al ready for h-phase at loop end
  }

  // --- h-phase: 32-way j split; thread (jr,dq) streams g[j][dq*4..] ---
  int jr = t >> 4;     // 0..31
  int dq = t & 15;
  float4 acc0 = {0,0,0,0}, acc1 = {0,0,0,0}, acc2 = {0,0,0,0};
  float4 acc3 = {0,0,0,0}, acc4 = {0,0,0,0}, acc5 = {0,0,0,0};
#pragma unroll 4
  for (int jj = 0; jj < NN / 32; jj++) {
    int j = jj * 32 + jr;
    float4 g4 = *(const float4*)(g + (size_t)j * DOUT + dq * 4);
    float a0 = al[0][j], a1 = al[1][j], a2 = al[2][j];
    float a3 = al[3][j], a4 = al[4][j], a5 = al[5][j];
    acc0.x = fmaf(a0, g4.x, acc0.x); acc0.y = fmaf(a0, g4.y, acc0.y);
    acc0.z = fmaf(a0, g4.z, acc0.z); acc0.w = fmaf(a0, g4.w, acc0.w);
    acc1.x = fmaf(a1, g4.x, acc1.x); acc1.y = fmaf(a1, g4.y, acc1.y);
    acc1.z = fmaf(a1, g4.z, acc1.z); acc1.w = fmaf(a1, g4.w, acc1.w);
    acc2.x = fmaf(a2, g4.x, acc2.x); acc2.y = fmaf(a2, g4.y, acc2.y);
    acc2.z = fmaf(a2, g4.z, acc2.z); acc2.w = fmaf(a2, g4.w, acc2.w);
    acc3.x = fmaf(a3, g4.x, acc3.x); acc3.y = fmaf(a3, g4.y, acc3.y);
    acc3.z = fmaf(a3, g4.z, acc3.z); acc3.w = fmaf(a3, g4.w, acc3.w);
    acc4.x = fmaf(a4, g4.x, acc4.x); acc4.y = fmaf(a4, g4.y, acc4.y);
    acc4.z = fmaf(a4, g4.z, acc4.z); acc4.w = fmaf(a4, g4.w, acc4.w);
    acc5.x = fmaf(a5, g4.x, acc5.x); acc5.y = fmaf(a5, g4.y, acc5.y);
    acc5.z = fmaf(a5, g4.z, acc5.z); acc5.w = fmaf(a5, g4.w, acc5.w);
  }
  *(float4*)(&part[jr][0][dq * 4]) = acc0;
  *(float4*)(&part[jr][1][dq * 4]) = acc1;
  *(float4*)(&part[jr][2][dq * 4]) = acc2;
  *(float4*)(&part[jr][3][dq * 4]) = acc3;
  *(float4*)(&part[jr][4][dq * 4]) = acc4;
  *(float4*)(&part[jr][5][dq * 4]) = acc5;
  __syncthreads();
  if (t < SROWS * DOUT) {
    int r = t >> 6, d = t & 63;
    float s = 0.f;
#pragma unroll
    for (int k = 0; k < 32; k++) s += part[k][r][d];
    h[(size_t)(r0 + r) * DOUT + d] = s;
  }
}

// ---------------- centroids (one block per class, 1024 threads) ----------------
__global__ __launch_bounds__(1024) void k_cent(const float* __restrict__ h,
                                               const int* __restrict__ labels,
                                               float* __restrict__ cent) {
  __shared__ float part[16][64];
  __shared__ int pc[16];
  int c = blockIdx.x, t = threadIdx.x;
  int d = t & 63, rq = t >> 6;
  float acc = 0.f;
  int cnt = 0;
#pragma unroll 4
  for (int r = rq; r < NSUP; r += 16) {
    int lab = labels[r];
    if (lab == c) { acc += h[(size_t)r * DOUT + d]; cnt++; }
  }
  part[rq][d] = acc;
  if (d == 0) pc[rq] = cnt;
  __syncthreads();
  if (t < 64) {
    float num = 0.f;
    int count = 0;
#pragma unroll
    for (int k = 0; k < 16; k++) { num += part[k][t]; count += pc[k]; }
    cent[c * DOUT + t] = (count > 0) ? (num / (float)count) : 0.f;
  }
}

// ---------------- scores = 1/(dist(query, centroid)+1e-10) ----------------
__global__ __launch_bounds__(256) void k_scores(const float* __restrict__ h,
                                                const float* __restrict__ cent,
                                                float* __restrict__ scores) {
  __shared__ float cl[NWAY * 65];
  __shared__ float hl[16 * 65];
  int t = threadIdx.x;
  int q0 = blockIdx.x * 16;
#pragma unroll
  for (int u = 0; u < 4; u++) {
    int f = t + u * 256;
    int row = f >> 6, k = f & 63;
    cl[row * 65 + k] = cent[f];
    hl[row * 65 + k] = h[(size_t)(NSUP + q0) * DOUT + f];
  }
  __syncthreads();
  int qr = t >> 4, c = t & 15;
  const float* hv = hl + qr * 65;
  const float* cv = cl + c * 65;
  float hh = 0.f, cc = 0.f, hc = 0.f;
#pragma unroll
  for (int k = 0; k < DOUT; k++) {
    float av = hv[k], bv = cv[k];
    hh = fmaf(av, av, hh);
    cc = fmaf(bv, bv, cc);
    hc = fmaf(av, bv, hc);
  }
  float d2 = fmaxf(hh + cc - 2.f * hc, 0.f);
  scores[q0 * NWAY + t] = 1.f / (sqrtf(d2) + 1e-10f);
}

extern "C" void kernel_launch(void* const* d_in, const int* in_sizes, int n_in,
                              void* d_out, int out_size, void* d_ws, size_t ws_size,
                              hipStream_t stream) {
  const float* hid = (const float*)d_in[0];
  const float* W = (const float*)d_in[1];
  const float* attw = (const float*)d_in[2];
  const int* labels = (const int*)d_in[3];
  const int* zda = (const int*)d_in[4];
  float* out = (float*)d_out;
  float* ws = (float*)d_ws;

  float* g = ws + WG;
  float* q = ws + WQ;
  int* code = (int*)(ws + WCODE);
  float* cent = ws + WCENT;
  float* scores = out + OFF_SCORES;
  float* h = out + OFF_H;
  float* a = out + OFF_A;

  hipLaunchKernelGGL(k_g, dim3(NN / 4), dim3(256), 0, stream, hid, W, attw, labels, zda, g, q, code);
  hipLaunchKernelGGL(k_e, dim3(NN / IB, NN / JBLK), dim3(256), 0, stream, g, q, code, attw, a);
  hipLaunchKernelGGL(k_smh, dim3(NN / SROWS), dim3(512), 0, stream, a, g, h);
  hipLaunchKernelGGL(k_cent, dim3(NWAY), dim3(1024), 0, stream, h, labels, cent);
  hipLaunchKernelGGL(k_scores, dim3(NSUP / 16), dim3(256), 0, stream, h, cent, scores);
}